// Round 3
// baseline (126.830 us; speedup 1.0000x reference)
//
#include <hip/hip_runtime.h>

#define UNITS 14336
#define IN_F 4096
#define PACKED 1024
#define CLIP_VAL 100.0f

typedef unsigned int uint32;

using bf16x8 = __attribute__((ext_vector_type(8))) short;   // 8 bf16 = 4 VGPRs
using f32x4  = __attribute__((ext_vector_type(4))) float;   // 4 fp32 acc

// fp32 -> bf16 round-to-nearest-even
__device__ inline unsigned short f2bf(float f) {
    uint32 u = __float_as_uint(f);
    u += 0x7FFFu + ((u >> 16) & 1u);
    return (unsigned short)(u >> 16);
}

__device__ inline uint32 pack2bf(float a, float b) {
    return (uint32)f2bf(a) | ((uint32)f2bf(b) << 16);
}

// SWAR unpack: one packed byte (int32 value 0..255, 4 crumbs little-endian)
// -> two uint32, each holding 2 bf16: r0 = {bf(c0), bf(c1)}, r1 = {bf(c2), bf(c3)}.
// crumb->bf16: 0->0x0000, 1->0x3F80 (+1), 2->0xBF80 (-1), 3->0x8000 (-0.0, harmless in MAC)
__device__ inline void unpack_byte(int v, uint32& r0, uint32& r1) {
    uint32 t0 = ((uint32)v & 3u) | (((uint32)v & 0xCu) << 14);         // c0 @ [1:0], c1 @ [17:16]
    uint32 t1 = (((uint32)v >> 4) & 3u) | (((uint32)v & 0xC0u) << 10); // c2, c3
    uint32 s0 = t0 >> 1;
    uint32 s1 = t1 >> 1;
    uint32 nz0 = (t0 ^ s0) & 0x00010001u;
    uint32 nz1 = (t1 ^ s1) & 0x00010001u;
    r0 = nz0 * 0x3F80u + ((s0 & 0x00010001u) << 15);
    r1 = nz1 * 0x3F80u + ((s1 & 0x00010001u) << 15);
}

__device__ inline float clipf(float y) {
    return fminf(fmaxf(y, -CLIP_VAL), CLIP_VAL);
}

// Fused single-kernel MFMA GEMM, v3.
//
// Grid: 448 blocks x 512 threads (8 waves). Block tile: 32 units x 32 batches.
// Wave wid owns K-range [wid*512, wid*512+512) = 8 "groups" of 64 crumbs.
//
// k-slot permutation trick: MFMA's reduction over k is order-invariant, so we
// permute crumbs->k-slots identically on A and B sides so that each lane's pw
// read is one contiguous dwordx4 (4 packed bytes = 16 crumbs). For group g:
//   lane (q,n) covers original k in [g*64 + q*16, g*64 + q*16 + 16):
//     k-step A (j=0..7): k = g*64 + q*16 + j      (pw elements g*16+q*4, +1)
//     k-step B (j=0..7): k = g*64 + q*16 + 8 + j  (pw elements g*16+q*4+2, +3)
// x side loads the same 16 floats [g*64+q*16, +16) and packs A/B frags to match.
//
// Per group per wave: 2 pw dwordx4 (unit groups g0/g1) + 8 x float4
// -> 8 MFMAs. LDS-reduce the 8 K-partial waves + fused scale/bias/clip.
__global__ __launch_bounds__(512) void ternary_mm_fused_kernel(
    const float* __restrict__ x,      // [32][4096] fp32
    const int*   __restrict__ pw,     // [UNITS][PACKED] packed bytes as int32
    const float* __restrict__ scale,
    const float* __restrict__ bias,
    float*       __restrict__ out) {
    __shared__ f32x4 red[8][4][64];   // [wave][frag g*2+h][lane] = 32 KB

    const int tid  = threadIdx.x;
    const int wid  = tid >> 6;           // 0..7 = K-split index
    const int lane = tid & 63;
    const int q    = lane >> 4;          // quad 0..3
    const int n    = lane & 15;
    const int u0   = blockIdx.x << 5;    // 32 units per block

    f32x4 acc00 = {0.f,0.f,0.f,0.f};     // units g0, batches h0
    f32x4 acc10 = {0.f,0.f,0.f,0.f};     // units g0, batches h1
    f32x4 acc01 = {0.f,0.f,0.f,0.f};     // units g1, batches h0
    f32x4 acc11 = {0.f,0.f,0.f,0.f};     // units g1, batches h1

    const int g0 = wid << 3;             // first group (of 64 total)
    // pw: element offset within row for group g, quad q: g*16 + q*4
    const int* pA = pw + (size_t)(u0 + n)      * PACKED + (g0 << 4) + (q << 2);
    const int* pB = pw + (size_t)(u0 + 16 + n) * PACKED + (g0 << 4) + (q << 2);
    // x: float offset for (h, group g): (h*16+n)*4096 + g*64 + q*16
    const float* x0 = x + (size_t)n        * IN_F + (g0 << 6) + (q << 4);
    const float* x1 = x + (size_t)(16 + n) * IN_F + (g0 << 6) + (q << 4);

    #pragma unroll 2
    for (int i = 0; i < 8; ++i) {
        int4 wA = *(const int4*)(pA + (i << 4));
        int4 wB = *(const int4*)(pB + (i << 4));
        const float4* xa = (const float4*)(x0 + (i << 6));
        const float4* xb = (const float4*)(x1 + (i << 6));
        float4 a0 = xa[0], a1 = xa[1], a2 = xa[2], a3 = xa[3];
        float4 b0 = xb[0], b1 = xb[1], b2 = xb[2], b3 = xb[3];

        // weight fragments: stepA from bytes .x/.y, stepB from bytes .z/.w
        uint4 fA_A, fA_B, fB_A, fB_B;
        unpack_byte(wA.x, fA_A.x, fA_A.y);
        unpack_byte(wA.y, fA_A.z, fA_A.w);
        unpack_byte(wA.z, fA_B.x, fA_B.y);
        unpack_byte(wA.w, fA_B.z, fA_B.w);
        unpack_byte(wB.x, fB_A.x, fB_A.y);
        unpack_byte(wB.y, fB_A.z, fB_A.w);
        unpack_byte(wB.z, fB_B.x, fB_B.y);
        unpack_byte(wB.w, fB_B.z, fB_B.w);

        // x fragments: stepA = floats 0-7, stepB = floats 8-15 (per h)
        uint4 xh0A, xh0B, xh1A, xh1B;
        xh0A.x = pack2bf(a0.x, a0.y); xh0A.y = pack2bf(a0.z, a0.w);
        xh0A.z = pack2bf(a1.x, a1.y); xh0A.w = pack2bf(a1.z, a1.w);
        xh0B.x = pack2bf(a2.x, a2.y); xh0B.y = pack2bf(a2.z, a2.w);
        xh0B.z = pack2bf(a3.x, a3.y); xh0B.w = pack2bf(a3.z, a3.w);
        xh1A.x = pack2bf(b0.x, b0.y); xh1A.y = pack2bf(b0.z, b0.w);
        xh1A.z = pack2bf(b1.x, b1.y); xh1A.w = pack2bf(b1.z, b1.w);
        xh1B.x = pack2bf(b2.x, b2.y); xh1B.y = pack2bf(b2.z, b2.w);
        xh1B.z = pack2bf(b3.x, b3.y); xh1B.w = pack2bf(b3.z, b3.w);

        bf16x8 vA_A = __builtin_bit_cast(bf16x8, fA_A);
        bf16x8 vA_B = __builtin_bit_cast(bf16x8, fA_B);
        bf16x8 vB_A = __builtin_bit_cast(bf16x8, fB_A);
        bf16x8 vB_B = __builtin_bit_cast(bf16x8, fB_B);
        bf16x8 v0A  = __builtin_bit_cast(bf16x8, xh0A);
        bf16x8 v0B  = __builtin_bit_cast(bf16x8, xh0B);
        bf16x8 v1A  = __builtin_bit_cast(bf16x8, xh1A);
        bf16x8 v1B  = __builtin_bit_cast(bf16x8, xh1B);

        acc00 = __builtin_amdgcn_mfma_f32_16x16x32_bf16(v0A, vA_A, acc00, 0, 0, 0);
        acc10 = __builtin_amdgcn_mfma_f32_16x16x32_bf16(v1A, vA_A, acc10, 0, 0, 0);
        acc01 = __builtin_amdgcn_mfma_f32_16x16x32_bf16(v0A, vB_A, acc01, 0, 0, 0);
        acc11 = __builtin_amdgcn_mfma_f32_16x16x32_bf16(v1A, vB_A, acc11, 0, 0, 0);
        acc00 = __builtin_amdgcn_mfma_f32_16x16x32_bf16(v0B, vA_B, acc00, 0, 0, 0);
        acc10 = __builtin_amdgcn_mfma_f32_16x16x32_bf16(v1B, vA_B, acc10, 0, 0, 0);
        acc01 = __builtin_amdgcn_mfma_f32_16x16x32_bf16(v0B, vB_B, acc01, 0, 0, 0);
        acc11 = __builtin_amdgcn_mfma_f32_16x16x32_bf16(v1B, vB_B, acc11, 0, 0, 0);
    }

    red[wid][0][lane] = acc00;   // f = g*2 + h
    red[wid][1][lane] = acc10;
    red[wid][2][lane] = acc01;
    red[wid][3][lane] = acc11;
    __syncthreads();

    // Reduce 8 K-partials + epilogue. 256 active threads, one per (frag, lane).
    if (tid < 256) {
        const int f = tid >> 6;          // g = f>>1, h = f&1
        const int l = tid & 63;
        f32x4 s = red[0][f][l];
        #pragma unroll
        for (int w = 1; w < 8; ++w) {
            f32x4 v = red[w][f][l];
            s[0] += v[0]; s[1] += v[1]; s[2] += v[2]; s[3] += v[3];
        }
        const int g = f >> 1;
        const int h = f & 1;
        const int u  = u0 + g * 16 + (l & 15);
        const int b0 = h * 16 + ((l >> 4) << 2);   // row = (lane>>4)*4 + reg
        const float sc = scale[u];
        const float bi = bias[u];
        float* o = out + (size_t)b0 * UNITS + u;
        o[0 * UNITS] = clipf(s[0] * sc + bi);
        o[1 * UNITS] = clipf(s[1] * sc + bi);
        o[2 * UNITS] = clipf(s[2] * sc + bi);
        o[3 * UNITS] = clipf(s[3] * sc + bi);
    }
}

extern "C" void kernel_launch(void* const* d_in, const int* in_sizes, int n_in,
                              void* d_out, int out_size, void* d_ws, size_t ws_size,
                              hipStream_t stream) {
    const float* x     = (const float*)d_in[0];
    const int*   pw    = (const int*)d_in[1];
    const float* scale = (const float*)d_in[2];
    const float* bias  = (const float*)d_in[3];
    float* out = (float*)d_out;
    (void)d_ws; (void)ws_size;

    ternary_mm_fused_kernel<<<UNITS / 32, 512, 0, stream>>>(x, pw, scale, bias, out);
}

// Round 4
// 109.719 us; speedup vs baseline: 1.1560x; 1.1560x over previous
//
#include <hip/hip_runtime.h>

#define UNITS 14336
#define IN_F 4096
#define PACKED 1024
#define CLIP_VAL 100.0f

typedef unsigned int uint32;

using bf16x8 = __attribute__((ext_vector_type(8))) short;   // 8 bf16 = 4 VGPRs
using f32x4  = __attribute__((ext_vector_type(4))) float;   // 4 fp32 acc

// fp32 -> bf16 round-to-nearest-even
__device__ inline unsigned short f2bf(float f) {
    uint32 u = __float_as_uint(f);
    u += 0x7FFFu + ((u >> 16) & 1u);
    return (unsigned short)(u >> 16);
}

__device__ inline uint32 pack2bf(float a, float b) {
    return (uint32)f2bf(a) | ((uint32)f2bf(b) << 16);
}

// SWAR unpack: one packed byte (int32 value 0..255, 4 crumbs little-endian)
// -> two uint32, each holding 2 bf16: r0 = {bf(c0), bf(c1)}, r1 = {bf(c2), bf(c3)}.
// crumb->bf16: 0->0x0000, 1->0x3F80 (+1), 2->0xBF80 (-1), 3->0x8000 (-0.0, harmless in MAC)
__device__ inline void unpack_byte(int v, uint32& r0, uint32& r1) {
    uint32 t0 = ((uint32)v & 3u) | (((uint32)v & 0xCu) << 14);         // c0 @ [1:0], c1 @ [17:16]
    uint32 t1 = (((uint32)v >> 4) & 3u) | (((uint32)v & 0xC0u) << 10); // c2, c3
    uint32 s0 = t0 >> 1;
    uint32 s1 = t1 >> 1;
    uint32 nz0 = (t0 ^ s0) & 0x00010001u;
    uint32 nz1 = (t1 ^ s1) & 0x00010001u;
    r0 = nz0 * 0x3F80u + ((s0 & 0x00010001u) << 15);
    r1 = nz1 * 0x3F80u + ((s1 & 0x00010001u) << 15);
}

__device__ inline float clipf(float y) {
    return fminf(fmaxf(y, -CLIP_VAL), CLIP_VAL);
}

// k-permuted fragment layout, shared by both kernels:
// "group" g in [0,64) covers original k in [g*64, g*64+64).
// Within a group, lane quad q and k-step s in {0,1}:
//   MFMA k-slot q*8+j  <->  original k = g*64 + q*16 + s*8 + j
// pw side: lane(q,n) reads one dwordx4 = bytes {P..P+3}, P = g*16 + q*4;
//   bytes P,P+1 -> step s=0 fragment, bytes P+2,P+3 -> step s=1 fragment.
// x side: granule idx = g*256 + s*128 + h*64 + lane holds 8 bf16:
//   j -> x[h*16 + (lane&15)][g*64 + (lane>>4)*16 + s*8 + j]

// Kernel 1: convert x [32][4096] fp32 -> bf16 in permuted A-fragment order.
__global__ __launch_bounds__(256) void convert_x_kernel(
    const float* __restrict__ x, uint4* __restrict__ ws) {
    int t = blockIdx.x * 256 + threadIdx.x;      // 0..16383 = granule idx
    int lane = t & 63;
    int h = (t >> 6) & 1;
    int s = (t >> 7) & 1;
    int g = t >> 8;
    int n = lane & 15;
    int q = lane >> 4;
    int b = h * 16 + n;
    int k0 = g * 64 + q * 16 + s * 8;
    const float4* src = (const float4*)(x + (size_t)b * IN_F + k0);
    float4 lo = src[0];
    float4 hi = src[1];
    uint4 o;
    o.x = pack2bf(lo.x, lo.y);
    o.y = pack2bf(lo.z, lo.w);
    o.z = pack2bf(hi.x, hi.y);
    o.w = pack2bf(hi.z, hi.w);
    ws[t] = o;
}

// Kernel 2: MFMA GEMM, v4.
// Grid: 896 blocks x 512 threads (8 waves). Block tile: 16 units x 32 batches.
// Wave wid owns groups [wid*8, wid*8+8) (K-split 8). Per iter: 1 pw dwordx4 +
// 4 x-frag dwordx4 -> 4 MFMAs into 2 accumulators. LDS-reduce + epilogue.
__global__ __launch_bounds__(512) void ternary_mm_kernel(
    const uint4* __restrict__ xw,     // permuted bf16 x fragments
    const int*   __restrict__ pw,     // [UNITS][PACKED] packed bytes as int32
    const float* __restrict__ scale,
    const float* __restrict__ bias,
    float*       __restrict__ out) {
    __shared__ f32x4 red[8][2][64];   // [wave][h][lane] = 16 KB

    const int tid  = threadIdx.x;
    const int wid  = tid >> 6;           // 0..7 = K-split index
    const int lane = tid & 63;
    const int q    = lane >> 4;          // quad 0..3
    const int n    = lane & 15;
    const int u0   = blockIdx.x << 4;    // 16 units per block

    f32x4 acc0 = {0.f,0.f,0.f,0.f};      // batches h0 (0-15)
    f32x4 acc1 = {0.f,0.f,0.f,0.f};      // batches h1 (16-31)

    const int g0 = wid << 3;             // first group (of 64 total)
    const int*   pA = pw + (size_t)(u0 + n) * PACKED + (g0 << 4) + (q << 2);
    const uint4* xb = xw + (g0 << 8) + lane;

    #pragma unroll 4
    for (int i = 0; i < 8; ++i) {
        int4 w4 = *(const int4*)(pA + (i << 4));
        uint4 x00 = xb[(i << 8)];            // s=0, h=0
        uint4 x01 = xb[(i << 8) + 64];       // s=0, h=1
        uint4 x10 = xb[(i << 8) + 128];      // s=1, h=0
        uint4 x11 = xb[(i << 8) + 192];      // s=1, h=1

        uint4 fA, fB;                        // step 0 / step 1 weight frags
        unpack_byte(w4.x, fA.x, fA.y);
        unpack_byte(w4.y, fA.z, fA.w);
        unpack_byte(w4.z, fB.x, fB.y);
        unpack_byte(w4.w, fB.z, fB.w);
        bf16x8 vA = __builtin_bit_cast(bf16x8, fA);
        bf16x8 vB = __builtin_bit_cast(bf16x8, fB);

        acc0 = __builtin_amdgcn_mfma_f32_16x16x32_bf16(
            __builtin_bit_cast(bf16x8, x00), vA, acc0, 0, 0, 0);
        acc1 = __builtin_amdgcn_mfma_f32_16x16x32_bf16(
            __builtin_bit_cast(bf16x8, x01), vA, acc1, 0, 0, 0);
        acc0 = __builtin_amdgcn_mfma_f32_16x16x32_bf16(
            __builtin_bit_cast(bf16x8, x10), vB, acc0, 0, 0, 0);
        acc1 = __builtin_amdgcn_mfma_f32_16x16x32_bf16(
            __builtin_bit_cast(bf16x8, x11), vB, acc1, 0, 0, 0);
    }

    red[wid][0][lane] = acc0;
    red[wid][1][lane] = acc1;
    __syncthreads();

    // Reduce 8 K-partials + epilogue. 128 active threads, one per (h, lane).
    if (tid < 128) {
        const int h = tid >> 6;
        const int l = tid & 63;
        f32x4 s = red[0][h][l];
        #pragma unroll
        for (int w = 1; w < 8; ++w) {
            f32x4 v = red[w][h][l];
            s[0] += v[0]; s[1] += v[1]; s[2] += v[2]; s[3] += v[3];
        }
        const int u  = u0 + (l & 15);
        const int b0 = h * 16 + ((l >> 4) << 2);   // row = (lane>>4)*4 + reg
        const float sc = scale[u];
        const float bi = bias[u];
        float* o = out + (size_t)b0 * UNITS + u;
        o[0 * UNITS] = clipf(s[0] * sc + bi);
        o[1 * UNITS] = clipf(s[1] * sc + bi);
        o[2 * UNITS] = clipf(s[2] * sc + bi);
        o[3 * UNITS] = clipf(s[3] * sc + bi);
    }
}

extern "C" void kernel_launch(void* const* d_in, const int* in_sizes, int n_in,
                              void* d_out, int out_size, void* d_ws, size_t ws_size,
                              hipStream_t stream) {
    const float* x     = (const float*)d_in[0];
    const int*   pw    = (const int*)d_in[1];
    const float* scale = (const float*)d_in[2];
    const float* bias  = (const float*)d_in[3];
    float* out = (float*)d_out;

    // ws usage: 32*4096 bf16 = 256 KB permuted x fragments
    uint4* xw = (uint4*)d_ws;

    convert_x_kernel<<<64, 256, 0, stream>>>(x, xw);
    ternary_mm_kernel<<<UNITS / 16, 512, 0, stream>>>(xw, pw, scale, bias, out);
}

// Round 5
// 105.740 us; speedup vs baseline: 1.1995x; 1.0376x over previous
//
#include <hip/hip_runtime.h>

#define UNITS 14336
#define IN_F 4096
#define PACKED 1024
#define CLIP_VAL 100.0f

typedef unsigned int uint32;

using bf16x8 = __attribute__((ext_vector_type(8))) short;   // 8 bf16 = 4 VGPRs
using f32x4  = __attribute__((ext_vector_type(4))) float;   // 4 fp32 acc

// fp32 -> bf16 round-to-nearest-even
__device__ inline unsigned short f2bf(float f) {
    uint32 u = __float_as_uint(f);
    u += 0x7FFFu + ((u >> 16) & 1u);
    return (unsigned short)(u >> 16);
}

__device__ inline uint32 pack2bf(float a, float b) {
    return (uint32)f2bf(a) | ((uint32)f2bf(b) << 16);
}

// SWAR unpack: one packed byte (int32 value 0..255, 4 crumbs little-endian)
// -> two uint32, each holding 2 bf16: r0 = {bf(c0), bf(c1)}, r1 = {bf(c2), bf(c3)}.
// crumb->bf16: 0->0x0000, 1->0x3F80 (+1), 2->0xBF80 (-1), 3->0x8000 (-0.0, harmless in MAC)
__device__ inline void unpack_byte(int v, uint32& r0, uint32& r1) {
    uint32 t0 = ((uint32)v & 3u) | (((uint32)v & 0xCu) << 14);         // c0 @ [1:0], c1 @ [17:16]
    uint32 t1 = (((uint32)v >> 4) & 3u) | (((uint32)v & 0xC0u) << 10); // c2, c3
    uint32 s0 = t0 >> 1;
    uint32 s1 = t1 >> 1;
    uint32 nz0 = (t0 ^ s0) & 0x00010001u;
    uint32 nz1 = (t1 ^ s1) & 0x00010001u;
    r0 = nz0 * 0x3F80u + ((s0 & 0x00010001u) << 15);
    r1 = nz1 * 0x3F80u + ((s1 & 0x00010001u) << 15);
}

__device__ inline float clipf(float y) {
    return fminf(fmaxf(y, -CLIP_VAL), CLIP_VAL);
}

// k-permuted fragment layout, shared by both kernels:
// "group" g in [0,64) covers original k in [g*64, g*64+64).
// Within a group, lane quad q and k-step s in {0,1}:
//   MFMA k-slot q*8+j  <->  original k = g*64 + q*16 + s*8 + j
// pw side: lane(q,n) reads one dwordx4 = bytes {P..P+3}, P = g*16 + q*4;
//   bytes P,P+1 -> step s=0 fragment, bytes P+2,P+3 -> step s=1 fragment.
// x side: granule idx = g*256 + s*128 + h*64 + lane holds 8 bf16:
//   j -> x[h*16 + (lane&15)][g*64 + (lane>>4)*16 + s*8 + j]

// Kernel 1: convert x [32][4096] fp32 -> bf16 in permuted A-fragment order.
__global__ __launch_bounds__(256) void convert_x_kernel(
    const float* __restrict__ x, uint4* __restrict__ ws) {
    int t = blockIdx.x * 256 + threadIdx.x;      // 0..16383 = granule idx
    int lane = t & 63;
    int h = (t >> 6) & 1;
    int s = (t >> 7) & 1;
    int g = t >> 8;
    int n = lane & 15;
    int q = lane >> 4;
    int b = h * 16 + n;
    int k0 = g * 64 + q * 16 + s * 8;
    const float4* src = (const float4*)(x + (size_t)b * IN_F + k0);
    float4 lo = src[0];
    float4 hi = src[1];
    uint4 o;
    o.x = pack2bf(lo.x, lo.y);
    o.y = pack2bf(lo.z, lo.w);
    o.z = pack2bf(hi.x, hi.y);
    o.w = pack2bf(hi.z, hi.w);
    ws[t] = o;
}

// Kernel 2: MFMA GEMM, v5 — max TLP.
// Grid: 896 blocks x 1024 threads (16 waves). Block tile: 16 units x 32 batches.
// Wave wid owns groups [wid*4, wid*4+4) (K-split 16). Per iter: 1 pw dwordx4 +
// 4 x-frag dwordx4 -> 4 MFMAs into 2 accumulators. LDS-reduce 16 partials.
// __launch_bounds__(1024, 8): 8 waves/EU -> VGPR<=64 -> 32 waves/CU resident.
__global__ __launch_bounds__(1024, 8) void ternary_mm_kernel(
    const uint4* __restrict__ xw,     // permuted bf16 x fragments
    const int*   __restrict__ pw,     // [UNITS][PACKED] packed bytes as int32
    const float* __restrict__ scale,
    const float* __restrict__ bias,
    float*       __restrict__ out) {
    __shared__ f32x4 red[16][2][64];  // [wave][h][lane] = 32 KB

    const int tid  = threadIdx.x;
    const int wid  = tid >> 6;           // 0..15 = K-split index
    const int lane = tid & 63;
    const int q    = lane >> 4;          // quad 0..3
    const int n    = lane & 15;
    const int u0   = blockIdx.x << 4;    // 16 units per block

    f32x4 acc0 = {0.f,0.f,0.f,0.f};      // batches h0 (0-15)
    f32x4 acc1 = {0.f,0.f,0.f,0.f};      // batches h1 (16-31)

    const int g0 = wid << 2;             // first group (of 64 total)
    const int*   pA = pw + (size_t)(u0 + n) * PACKED + (g0 << 4) + (q << 2);
    const uint4* xb = xw + (g0 << 8) + lane;

    #pragma unroll
    for (int i = 0; i < 4; ++i) {
        int4 w4 = *(const int4*)(pA + (i << 4));
        uint4 x00 = xb[(i << 8)];            // s=0, h=0
        uint4 x01 = xb[(i << 8) + 64];       // s=0, h=1
        uint4 x10 = xb[(i << 8) + 128];      // s=1, h=0
        uint4 x11 = xb[(i << 8) + 192];      // s=1, h=1

        uint4 fA, fB;                        // step 0 / step 1 weight frags
        unpack_byte(w4.x, fA.x, fA.y);
        unpack_byte(w4.y, fA.z, fA.w);
        unpack_byte(w4.z, fB.x, fB.y);
        unpack_byte(w4.w, fB.z, fB.w);
        bf16x8 vA = __builtin_bit_cast(bf16x8, fA);
        bf16x8 vB = __builtin_bit_cast(bf16x8, fB);

        acc0 = __builtin_amdgcn_mfma_f32_16x16x32_bf16(
            __builtin_bit_cast(bf16x8, x00), vA, acc0, 0, 0, 0);
        acc1 = __builtin_amdgcn_mfma_f32_16x16x32_bf16(
            __builtin_bit_cast(bf16x8, x01), vA, acc1, 0, 0, 0);
        acc0 = __builtin_amdgcn_mfma_f32_16x16x32_bf16(
            __builtin_bit_cast(bf16x8, x10), vB, acc0, 0, 0, 0);
        acc1 = __builtin_amdgcn_mfma_f32_16x16x32_bf16(
            __builtin_bit_cast(bf16x8, x11), vB, acc1, 0, 0, 0);
    }

    red[wid][0][lane] = acc0;
    red[wid][1][lane] = acc1;
    __syncthreads();

    // Reduce 16 K-partials + epilogue. 128 active threads, one per (h, lane).
    if (tid < 128) {
        const int h = tid >> 6;
        const int l = tid & 63;
        f32x4 s = red[0][h][l];
        #pragma unroll
        for (int w = 1; w < 16; ++w) {
            f32x4 v = red[w][h][l];
            s[0] += v[0]; s[1] += v[1]; s[2] += v[2]; s[3] += v[3];
        }
        const int u  = u0 + (l & 15);
        const int b0 = h * 16 + ((l >> 4) << 2);   // row = (lane>>4)*4 + reg
        const float sc = scale[u];
        const float bi = bias[u];
        float* o = out + (size_t)b0 * UNITS + u;
        o[0 * UNITS] = clipf(s[0] * sc + bi);
        o[1 * UNITS] = clipf(s[1] * sc + bi);
        o[2 * UNITS] = clipf(s[2] * sc + bi);
        o[3 * UNITS] = clipf(s[3] * sc + bi);
    }
}

extern "C" void kernel_launch(void* const* d_in, const int* in_sizes, int n_in,
                              void* d_out, int out_size, void* d_ws, size_t ws_size,
                              hipStream_t stream) {
    const float* x     = (const float*)d_in[0];
    const int*   pw    = (const int*)d_in[1];
    const float* scale = (const float*)d_in[2];
    const float* bias  = (const float*)d_in[3];
    float* out = (float*)d_out;

    // ws usage: 32*4096 bf16 = 256 KB permuted x fragments
    uint4* xw = (uint4*)d_ws;

    convert_x_kernel<<<64, 256, 0, stream>>>(x, xw);
    ternary_mm_kernel<<<UNITS / 16, 1024, 0, stream>>>(xw, pw, scale, bias, out);
}